// Round 4
// baseline (98.296 us; speedup 1.0000x reference)
//
#include <hip/hip_runtime.h>
#include <stdint.h>
#include <stddef.h>

// Problem constants (reference: M=16, K=8192, N=8192, GROUP=128)
#define MM 16
#define KK 8192
#define NN 8192
#define GROUP_SZ 128
#define NGROUP 64            // K / GROUP
#define KPACK 1024           // K / 8 packed int32 per output row
#define NWAVE 8              // waves per block (one K/8 slice each)
#define KCH (KK / NWAVE)     // 1024 k per wave
#define GPW (KCH / GROUP_SZ) // 8 groups per wave

typedef _Float16 half8_t __attribute__((ext_vector_type(8)));
typedef _Float16 half2_t __attribute__((ext_vector_type(2)));
typedef float float4_t __attribute__((ext_vector_type(4)));
typedef uint32_t uint4_t __attribute__((ext_vector_type(4)));

// XOR swizzle on the 16B-chunk index (256 chunks per buffer):
// fc bits: [7:6]=j, [5:4]=quad, [3:0]=m. Mix upper bits into [2:0] so both
// ds_write_b128 and ds_read_b128 spread over the 8 bank-groups. Bijective.
__device__ __forceinline__ int swz(int fc) {
    return fc ^ (((fc >> 3) ^ (fc >> 6)) & 7);
}

// ---------------------------------------------------------------------------
// FUSED single-launch kernel: 512 blocks (one 16-col n-tile) x 512 threads
// (8 waves). Wave w owns k-slice [w*1024, (w+1)*1024) = 8 groups.
//
// vs round-3 (same geometry/math, validated): the per-group serial latency
// chain is cut down:
//  - all cross-lane shuffles (group-sum fold + broadcast) moved OUT of the
//    loop into the epilogue, where the 48 ds_bpermutes pipeline
//  - double-buffered wave-private staging: read group g (written last iter),
//    write group g+1 -> LDS write->read round-trip off the critical path
//  - scales/zeros for all 8 groups hoisted to the prologue
//  - two fdot2 chains (8-deep), even/odd MFMA accumulators (2-deep)
//  - full unroll keeps pg[8] statically indexed (registers, not scratch)
// ---------------------------------------------------------------------------
__global__ __launch_bounds__(512, 4) void wq_fused(
        const float* __restrict__ x,
        const int* __restrict__ qweight,
        const float* __restrict__ scales,
        const float* __restrict__ zeros,
        const float* __restrict__ bias,
        float* __restrict__ out) {
    __shared__ alignas(16) _Float16 stage[NWAVE * 4096]; // 64 KB: 8KB/wave (2 bufs)
    __shared__ float red[NWAVE * 256];                   // 8 KB

    const int t     = threadIdx.x;
    const int w     = t >> 6;
    const int lane  = t & 63;
    const int ntile = blockIdx.x;
    const int nlo   = lane & 15;
    const int quad  = lane >> 4;
    const int n     = ntile * 16 + nlo;

    // ---- staging geometry (writer side) ----
    // lane -> rows lh, lh+4, lh+8, lh+12 (via u), k-part l4: k0 = l4*8
    const int l4    = lane & 15;
    const int lh    = lane >> 4;
    const int quadw = l4 >> 2;
    const int jj    = l4 & 3;
    const float* xs = x + (size_t)lh * KK + w * KCH + l4 * 8;

    half8_t* sb = (half8_t*)(stage + w * 4096);
    int wfc[4], rfc[4];
    #pragma unroll
    for (int u = 0; u < 4; ++u)
        wfc[u] = swz(jj * 64 + quadw * 16 + 4 * u + lh);
    #pragma unroll
    for (int j = 0; j < 4; ++j)
        rfc[j] = swz(j * 64 + lane);

    // this wave's qweight slice: row n, ints [w*128, w*128+128)
    const int* qrow = qweight + (size_t)n * KPACK + w * (KCH / 8);
    const int g0 = w * GPW;

    // ---- hoisted per-group scale / zero-correction coefficients ----
    float sA[GPW], cA[GPW];
    #pragma unroll
    for (int g = 0; g < GPW; ++g) {
        const float sg = scales[(size_t)(g0 + g) * NN + n];
        const float zg = zeros[(size_t)(g0 + g) * NN + n];
        sA[g] = sg;
        cA[g] = zg - 1024.0f * sg;
    }

    // ---- prologue: stage group 0 into buf0, prefetch group 1 ----
    float4_t xa[4], xb[4];
    #pragma unroll
    for (int u = 0; u < 4; ++u) {
        xa[u] = *(const float4_t*)(xs + (size_t)u * 4 * KK);
        xb[u] = *(const float4_t*)(xs + (size_t)u * 4 * KK + 4);
    }
    uint4_t bwc = *(const uint4_t*)(qrow + quad * 4);

    #pragma unroll
    for (int u = 0; u < 4; ++u) {
        half8_t st;
        st[0] = (_Float16)xa[u][0]; st[1] = (_Float16)xb[u][0];
        st[2] = (_Float16)xa[u][1]; st[3] = (_Float16)xb[u][1];
        st[4] = (_Float16)xa[u][2]; st[5] = (_Float16)xb[u][2];
        st[6] = (_Float16)xa[u][3]; st[7] = (_Float16)xb[u][3];
        sb[wfc[u]] = st;
    }
    #pragma unroll
    for (int u = 0; u < 4; ++u) {
        xa[u] = *(const float4_t*)(xs + (size_t)u * 4 * KK + GROUP_SZ);
        xb[u] = *(const float4_t*)(xs + (size_t)u * 4 * KK + GROUP_SZ + 4);
    }
    uint4_t bwn = *(const uint4_t*)(qrow + 16 + quad * 4);

    float4_t outacc = {0.f, 0.f, 0.f, 0.f};
    float pg[GPW];

    #pragma unroll
    for (int g = 0; g < GPW; ++g) {
        const int rb = (g & 1) << 8;        // read-buffer chunk offset
        const int wb = ((g + 1) & 1) << 8;  // write-buffer chunk offset

        // fragment reads: buffer filled last iteration (or prologue)
        half8_t af[4];
        #pragma unroll
        for (int j = 0; j < 4; ++j)
            af[j] = sb[rb + rfc[j]];

        // stage group g+1 (cvt of prefetched regs; write->read gap = 1 iter)
        if (g + 1 < GPW) {
            #pragma unroll
            for (int u = 0; u < 4; ++u) {
                half8_t st;
                st[0] = (_Float16)xa[u][0]; st[1] = (_Float16)xb[u][0];
                st[2] = (_Float16)xa[u][1]; st[3] = (_Float16)xb[u][1];
                st[4] = (_Float16)xa[u][2]; st[5] = (_Float16)xb[u][2];
                st[6] = (_Float16)xa[u][3]; st[7] = (_Float16)xb[u][3];
                sb[wb + wfc[u]] = st;
            }
        }
        // prefetch group g+2 x
        if (g + 2 < GPW) {
            #pragma unroll
            for (int u = 0; u < 4; ++u) {
                xa[u] = *(const float4_t*)(xs + (size_t)u * 4 * KK + (g + 2) * GROUP_SZ);
                xb[u] = *(const float4_t*)(xs + (size_t)u * 4 * KK + (g + 2) * GROUP_SZ + 4);
            }
        }

        float4_t ge = {0.f, 0.f, 0.f, 0.f};
        float4_t go = {0.f, 0.f, 0.f, 0.f};
        float p0 = 0.f, p1 = 0.f;
        #pragma unroll
        for (int j = 0; j < 4; ++j) {
            const half2_t one = {(_Float16)1.f, (_Float16)1.f};
            half2_t q0 = {af[j][0], af[j][1]}, q1 = {af[j][2], af[j][3]};
            half2_t q2 = {af[j][4], af[j][5]}, q3 = {af[j][6], af[j][7]};
#if __has_builtin(__builtin_amdgcn_fdot2)
            if (j < 2) {
                p0 = __builtin_amdgcn_fdot2(q0, one, p0, false);
                p0 = __builtin_amdgcn_fdot2(q1, one, p0, false);
                p0 = __builtin_amdgcn_fdot2(q2, one, p0, false);
                p0 = __builtin_amdgcn_fdot2(q3, one, p0, false);
            } else {
                p1 = __builtin_amdgcn_fdot2(q0, one, p1, false);
                p1 = __builtin_amdgcn_fdot2(q1, one, p1, false);
                p1 = __builtin_amdgcn_fdot2(q2, one, p1, false);
                p1 = __builtin_amdgcn_fdot2(q3, one, p1, false);
            }
#else
            float acc = (float)af[j][0] + (float)af[j][1] + (float)af[j][2]
                      + (float)af[j][3] + (float)af[j][4] + (float)af[j][5]
                      + (float)af[j][6] + (float)af[j][7];
            if (j < 2) p0 += acc; else p1 += acc;
#endif
            const uint32_t d = bwc[j];
            uint4_t bb;
            bb.x = ( d         & 0x000F000Fu) | 0x64006400u;  // nibbles (0,4)
            bb.y = ((d >> 4)   & 0x000F000Fu) | 0x64006400u;  // (1,5)
            bb.z = ((d >> 8)   & 0x000F000Fu) | 0x64006400u;  // (2,6)
            bb.w = ((d >> 12)  & 0x000F000Fu) | 0x64006400u;  // (3,7)
            if ((j & 1) == 0)
                ge = __builtin_amdgcn_mfma_f32_16x16x32_f16(
                         af[j], __builtin_bit_cast(half8_t, bb), ge, 0, 0, 0);
            else
                go = __builtin_amdgcn_mfma_f32_16x16x32_f16(
                         af[j], __builtin_bit_cast(half8_t, bb), go, 0, 0, 0);
        }
        pg[g] = p0 + p1;
        #pragma unroll
        for (int r = 0; r < 4; ++r)
            outacc[r] = fmaf(sA[g], ge[r] + go[r], outacc[r]);

        // shift B pipeline
        if (g + 1 < GPW) bwc = bwn;
        if (g + 2 < GPW) bwn = *(const uint4_t*)(qrow + (g + 2) * 16 + quad * 4);
    }

    // ---- epilogue: deferred zero-point correction (shuffles pipeline) ----
    // fold quad-parts: every lane ends holding sxg[m=nlo][g0+g]
    #pragma unroll
    for (int g = 0; g < GPW; ++g) {
        pg[g] += __shfl_xor(pg[g], 16, 64);
        pg[g] += __shfl_xor(pg[g], 32, 64);
    }
    // outacc[r] (D-row m = quad*4+r): add sum_g cA[g] * sxg[m][g]
    // (cA uses THIS lane's n; shuffle carries only the n-independent row sum)
    #pragma unroll
    for (int r = 0; r < 4; ++r) {
        float acc = outacc[r];
        #pragma unroll
        for (int g = 0; g < GPW; ++g)
            acc = fmaf(cA[g], __shfl(pg[g], quad * 4 + r, 64), acc);
        outacc[r] = acc;
    }

    // C/D layout: col = lane&15, row = quad*4 + r  -> red[w][row*16 + col]
    #pragma unroll
    for (int r = 0; r < 4; ++r)
        red[w * 256 + (quad * 4 + r) * 16 + nlo] = outacc[r];
    __syncthreads();

    if (t < 256) {
        const int m  = t >> 4;
        const int nn = t & 15;
        float v = bias[ntile * 16 + nn];
        #pragma unroll
        for (int ww = 0; ww < NWAVE; ++ww) v += red[ww * 256 + t];
        out[(size_t)m * NN + ntile * 16 + nn] = v;
    }
}

// ---------------------------------------------------------------------------
extern "C" void kernel_launch(void* const* d_in, const int* in_sizes, int n_in,
                              void* d_out, int out_size, void* d_ws, size_t ws_size,
                              hipStream_t stream) {
    const float* x      = (const float*)d_in[0];   // [16, 8192]
    const int*   qw     = (const int*)d_in[1];     // [8192, 1024]
    const float* scales = (const float*)d_in[2];   // [64, 8192]
    const float* zeros  = (const float*)d_in[3];   // [64, 8192]
    const float* bias   = (const float*)d_in[4];   // [8192]
    float* out = (float*)d_out;                    // [16, 8192] fp32
    (void)d_ws; (void)ws_size; (void)in_sizes; (void)n_in;

    wq_fused<<<NN / 16, 512, 0, stream>>>(x, qw, scales, zeros, bias, out);
}

// Round 5
// 94.566 us; speedup vs baseline: 1.0394x; 1.0394x over previous
//
#include <hip/hip_runtime.h>
#include <stdint.h>
#include <stddef.h>

// Problem constants (reference: M=16, K=8192, N=8192, GROUP=128)
#define MM 16
#define KK 8192
#define NN 8192
#define GROUP_SZ 128
#define NGROUP 64            // K / GROUP
#define KPACK 1024           // K / 8 packed int32 per output row
#define NWAVE 8              // waves per block (one K/8 slice each)
#define KCH (KK / NWAVE)     // 1024 k per wave
#define GPW (KCH / GROUP_SZ) // 8 groups per wave
#define CPB 32               // n-cols per block (two 16-col MFMA tiles)

typedef _Float16 half8_t __attribute__((ext_vector_type(8)));
typedef _Float16 half2_t __attribute__((ext_vector_type(2)));
typedef float float4_t __attribute__((ext_vector_type(4)));
typedef uint32_t uint4_t __attribute__((ext_vector_type(4)));

// XOR swizzle on the 16B-chunk index (256 chunks per buffer). Bijective;
// spreads both ds_write_b128 and ds_read_b128 over the 8 bank-groups.
__device__ __forceinline__ int swz(int fc) {
    return fc ^ (((fc >> 3) ^ (fc >> 6)) & 7);
}

// ---------------------------------------------------------------------------
// FUSED kernel, 256 blocks (one 32-col n-tile-pair) x 512 threads (8 waves).
// Wave w owns k-slice [w*1024, (w+1)*1024) = 8 groups, EXACTLY as round 4,
// but amortizes each staged A-fragment over TWO n-tiles (n, n+16):
//   per-CU L2-served bytes 1168 KB -> 656 KB (x re-read amplification was
//   268 MB vs 33.5 MB of qweight; rounds 0/3/4 all pinned at ~29 us by this
//   byte volume against the per-CU outstanding-miss ceiling).
// Math per tile is identical to the validated round-3/4 kernel (rte f16
// cvts, fdot2 group x-sums for the exact zero-point correction, f32 group
// accumulators, deferred epilogue shuffles).
// ---------------------------------------------------------------------------
__global__ __launch_bounds__(512, 2) void wq_fused(
        const float* __restrict__ x,
        const int* __restrict__ qweight,
        const float* __restrict__ scales,
        const float* __restrict__ zeros,
        const float* __restrict__ bias,
        float* __restrict__ out) {
    __shared__ alignas(16) _Float16 stage[NWAVE * 4096]; // 64 KB: 8KB/wave (2 bufs)
    __shared__ float red[2 * NWAVE * 256];               // 16 KB (tile A, tile B)

    const int t     = threadIdx.x;
    const int w     = t >> 6;
    const int lane  = t & 63;
    const int ntile = blockIdx.x;
    const int nlo   = lane & 15;
    const int quad  = lane >> 4;
    const int n0    = ntile * CPB + nlo;        // tile A column
    const int n1    = n0 + 16;                  // tile B column

    // ---- staging geometry (writer side; unchanged from round 4) ----
    const int l4    = lane & 15;
    const int lh    = lane >> 4;
    const int quadw = l4 >> 2;
    const int jj    = l4 & 3;
    const float* xs = x + (size_t)lh * KK + w * KCH + l4 * 8;

    half8_t* sb = (half8_t*)(stage + w * 4096);
    int wfc[4], rfc[4];
    #pragma unroll
    for (int u = 0; u < 4; ++u)
        wfc[u] = swz(jj * 64 + quadw * 16 + 4 * u + lh);
    #pragma unroll
    for (int j = 0; j < 4; ++j)
        rfc[j] = swz(j * 64 + lane);

    // qweight slices for both tiles: row n, ints [w*128, w*128+128)
    const int* qrowA = qweight + (size_t)n0 * KPACK + w * (KCH / 8);
    const int* qrowB = qweight + (size_t)n1 * KPACK + w * (KCH / 8);
    const int g0 = w * GPW;

    // ---- hoisted per-group scale / zero-correction coefficients ----
    float sA0[GPW], cA0[GPW], sA1[GPW], cA1[GPW];
    #pragma unroll
    for (int g = 0; g < GPW; ++g) {
        const size_t ro = (size_t)(g0 + g) * NN;
        const float sa = scales[ro + n0], za = zeros[ro + n0];
        const float sbc = scales[ro + n1], zb = zeros[ro + n1];
        sA0[g] = sa; cA0[g] = za - 1024.0f * sa;
        sA1[g] = sbc; cA1[g] = zb - 1024.0f * sbc;
    }

    // ---- prologue: stage group 0 into buf0, prefetch group 1 ----
    float4_t xa[4], xb[4];
    #pragma unroll
    for (int u = 0; u < 4; ++u) {
        xa[u] = *(const float4_t*)(xs + (size_t)u * 4 * KK);
        xb[u] = *(const float4_t*)(xs + (size_t)u * 4 * KK + 4);
    }
    uint4_t bwcA = *(const uint4_t*)(qrowA + quad * 4);
    uint4_t bwcB = *(const uint4_t*)(qrowB + quad * 4);

    #pragma unroll
    for (int u = 0; u < 4; ++u) {
        half8_t st;
        st[0] = (_Float16)xa[u][0]; st[1] = (_Float16)xb[u][0];
        st[2] = (_Float16)xa[u][1]; st[3] = (_Float16)xb[u][1];
        st[4] = (_Float16)xa[u][2]; st[5] = (_Float16)xb[u][2];
        st[6] = (_Float16)xa[u][3]; st[7] = (_Float16)xb[u][3];
        sb[wfc[u]] = st;
    }
    #pragma unroll
    for (int u = 0; u < 4; ++u) {
        xa[u] = *(const float4_t*)(xs + (size_t)u * 4 * KK + GROUP_SZ);
        xb[u] = *(const float4_t*)(xs + (size_t)u * 4 * KK + GROUP_SZ + 4);
    }
    uint4_t bwnA = *(const uint4_t*)(qrowA + 16 + quad * 4);
    uint4_t bwnB = *(const uint4_t*)(qrowB + 16 + quad * 4);

    float4_t outA = {0.f, 0.f, 0.f, 0.f};
    float4_t outB = {0.f, 0.f, 0.f, 0.f};
    float pg[GPW];

    #pragma unroll
    for (int g = 0; g < GPW; ++g) {
        const int rb = (g & 1) << 8;        // read-buffer chunk offset
        const int wb = ((g + 1) & 1) << 8;  // write-buffer chunk offset

        // fragment reads: buffer filled last iteration (or prologue)
        half8_t af[4];
        #pragma unroll
        for (int j = 0; j < 4; ++j)
            af[j] = sb[rb + rfc[j]];

        // stage group g+1 (cvt of prefetched regs; write->read gap = 1 iter)
        if (g + 1 < GPW) {
            #pragma unroll
            for (int u = 0; u < 4; ++u) {
                half8_t st;
                st[0] = (_Float16)xa[u][0]; st[1] = (_Float16)xb[u][0];
                st[2] = (_Float16)xa[u][1]; st[3] = (_Float16)xb[u][1];
                st[4] = (_Float16)xa[u][2]; st[5] = (_Float16)xb[u][2];
                st[6] = (_Float16)xa[u][3]; st[7] = (_Float16)xb[u][3];
                sb[wb + wfc[u]] = st;
            }
        }
        // prefetch group g+2 x
        if (g + 2 < GPW) {
            #pragma unroll
            for (int u = 0; u < 4; ++u) {
                xa[u] = *(const float4_t*)(xs + (size_t)u * 4 * KK + (g + 2) * GROUP_SZ);
                xb[u] = *(const float4_t*)(xs + (size_t)u * 4 * KK + (g + 2) * GROUP_SZ + 4);
            }
        }

        float4_t gaccA = {0.f, 0.f, 0.f, 0.f};
        float4_t gaccB = {0.f, 0.f, 0.f, 0.f};
        float p0 = 0.f, p1 = 0.f;
        #pragma unroll
        for (int j = 0; j < 4; ++j) {
            const half2_t one = {(_Float16)1.f, (_Float16)1.f};
            half2_t q0 = {af[j][0], af[j][1]}, q1 = {af[j][2], af[j][3]};
            half2_t q2 = {af[j][4], af[j][5]}, q3 = {af[j][6], af[j][7]};
#if __has_builtin(__builtin_amdgcn_fdot2)
            if (j < 2) {
                p0 = __builtin_amdgcn_fdot2(q0, one, p0, false);
                p0 = __builtin_amdgcn_fdot2(q1, one, p0, false);
                p0 = __builtin_amdgcn_fdot2(q2, one, p0, false);
                p0 = __builtin_amdgcn_fdot2(q3, one, p0, false);
            } else {
                p1 = __builtin_amdgcn_fdot2(q0, one, p1, false);
                p1 = __builtin_amdgcn_fdot2(q1, one, p1, false);
                p1 = __builtin_amdgcn_fdot2(q2, one, p1, false);
                p1 = __builtin_amdgcn_fdot2(q3, one, p1, false);
            }
#else
            float acc = (float)af[j][0] + (float)af[j][1] + (float)af[j][2]
                      + (float)af[j][3] + (float)af[j][4] + (float)af[j][5]
                      + (float)af[j][6] + (float)af[j][7];
            if (j < 2) p0 += acc; else p1 += acc;
#endif
            // tile A dequant + MFMA
            {
                const uint32_t d = bwcA[j];
                uint4_t bb;
                bb.x = ( d         & 0x000F000Fu) | 0x64006400u;
                bb.y = ((d >> 4)   & 0x000F000Fu) | 0x64006400u;
                bb.z = ((d >> 8)   & 0x000F000Fu) | 0x64006400u;
                bb.w = ((d >> 12)  & 0x000F000Fu) | 0x64006400u;
                gaccA = __builtin_amdgcn_mfma_f32_16x16x32_f16(
                            af[j], __builtin_bit_cast(half8_t, bb), gaccA, 0, 0, 0);
            }
            // tile B dequant + MFMA (independent chain, interleaves with A)
            {
                const uint32_t d = bwcB[j];
                uint4_t bb;
                bb.x = ( d         & 0x000F000Fu) | 0x64006400u;
                bb.y = ((d >> 4)   & 0x000F000Fu) | 0x64006400u;
                bb.z = ((d >> 8)   & 0x000F000Fu) | 0x64006400u;
                bb.w = ((d >> 12)  & 0x000F000Fu) | 0x64006400u;
                gaccB = __builtin_amdgcn_mfma_f32_16x16x32_f16(
                            af[j], __builtin_bit_cast(half8_t, bb), gaccB, 0, 0, 0);
            }
        }
        pg[g] = p0 + p1;
        #pragma unroll
        for (int r = 0; r < 4; ++r) {
            outA[r] = fmaf(sA0[g], gaccA[r], outA[r]);
            outB[r] = fmaf(sA1[g], gaccB[r], outB[r]);
        }

        // shift B pipelines
        if (g + 1 < GPW) { bwcA = bwnA; bwcB = bwnB; }
        if (g + 2 < GPW) {
            bwnA = *(const uint4_t*)(qrowA + (g + 2) * 16 + quad * 4);
            bwnB = *(const uint4_t*)(qrowB + (g + 2) * 16 + quad * 4);
        }
    }

    // ---- epilogue: deferred zero-point correction (shuffles pipeline) ----
    #pragma unroll
    for (int g = 0; g < GPW; ++g) {
        pg[g] += __shfl_xor(pg[g], 16, 64);
        pg[g] += __shfl_xor(pg[g], 32, 64);
    }
    // outX[r] (D-row m = quad*4+r): add sum_g cX[g] * sxg[m][g]
    // (broadcast carries only the n-independent row sum; reused by both tiles)
    #pragma unroll
    for (int r = 0; r < 4; ++r) {
        float accA = outA[r], accB = outB[r];
        #pragma unroll
        for (int g = 0; g < GPW; ++g) {
            const float sx = __shfl(pg[g], quad * 4 + r, 64);
            accA = fmaf(cA0[g], sx, accA);
            accB = fmaf(cA1[g], sx, accB);
        }
        outA[r] = accA; outB[r] = accB;
    }

    // C/D layout: col = lane&15, row = quad*4 + r
    #pragma unroll
    for (int r = 0; r < 4; ++r) {
        red[w * 256 + (quad * 4 + r) * 16 + nlo]        = outA[r];
        red[2048 + w * 256 + (quad * 4 + r) * 16 + nlo] = outB[r];
    }
    __syncthreads();

    if (t < 256) {
        const int m  = t >> 4;
        const int nn = t & 15;
        float vA = bias[ntile * CPB + nn];
        float vB = bias[ntile * CPB + 16 + nn];
        #pragma unroll
        for (int ww = 0; ww < NWAVE; ++ww) {
            vA += red[ww * 256 + t];
            vB += red[2048 + ww * 256 + t];
        }
        out[(size_t)m * NN + ntile * CPB + nn]      = vA;
        out[(size_t)m * NN + ntile * CPB + 16 + nn] = vB;
    }
}

// ---------------------------------------------------------------------------
extern "C" void kernel_launch(void* const* d_in, const int* in_sizes, int n_in,
                              void* d_out, int out_size, void* d_ws, size_t ws_size,
                              hipStream_t stream) {
    const float* x      = (const float*)d_in[0];   // [16, 8192]
    const int*   qw     = (const int*)d_in[1];     // [8192, 1024]
    const float* scales = (const float*)d_in[2];   // [64, 8192]
    const float* zeros  = (const float*)d_in[3];   // [64, 8192]
    const float* bias   = (const float*)d_in[4];   // [8192]
    float* out = (float*)d_out;                    // [16, 8192] fp32
    (void)d_ws; (void)ws_size; (void)in_sizes; (void)n_in;

    wq_fused<<<NN / CPB, 512, 0, stream>>>(x, qw, scales, zeros, bias, out);
}